// Round 2
// baseline (1667.061 us; speedup 1.0000x reference)
//
#include <hip/hip_runtime.h>
#include <hip/hip_bf16.h>

// Problem constants
#define BB   2
#define SS   4096
#define DD   256
#define HH   8
#define DKK  32
#define DFFC 1024
#define BS   (BB*SS)          // 8192 rows

// softmax scale folded into q, in log2 domain: 1/sqrt(32) * 1/ln(2)
#define SCALE2 (0.17677669529663689f * 1.4426950408889634f)

// ---------------------------------------------------------------------------
// K1: QKV projection.  src[BS,256] x {Wq,Wk,Wv}[H,256,32] -> q,k,v [B,H,S,32]
// 16 rows per block, 256 threads; thread = (h, kk) column of all three mats.
// ---------------------------------------------------------------------------
__global__ __launch_bounds__(256) void qkv_proj_k(
    const float* __restrict__ src,
    const float* __restrict__ Wq, const float* __restrict__ bq,
    const float* __restrict__ Wk, const float* __restrict__ bk,
    const float* __restrict__ Wv, const float* __restrict__ bv,
    float* __restrict__ q, float* __restrict__ k, float* __restrict__ v)
{
    __shared__ float rowbuf[16][DD];          // 16 KB
    const int tid = threadIdx.x;
    const int r0  = blockIdx.x * 16;

    // stage 16 rows (4096 floats = 1024 float4)
    const float4* sv = (const float4*)(src + (size_t)r0 * DD);
    float4* rb = (float4*)&rowbuf[0][0];
#pragma unroll
    for (int i = 0; i < 4; ++i) rb[i * 256 + tid] = sv[i * 256 + tid];
    __syncthreads();

    const int h  = tid >> 5;
    const int kk = tid & 31;
    const float* wq = Wq + (size_t)h * DD * DKK + kk;
    const float* wk = Wk + (size_t)h * DD * DKK + kk;
    const float* wv = Wv + (size_t)h * DD * DKK + kk;

    float aq[16], ak[16], av[16];
#pragma unroll
    for (int m = 0; m < 16; ++m) { aq[m] = 0.f; ak[m] = 0.f; av[m] = 0.f; }

    for (int d4 = 0; d4 < DD / 4; ++d4) {
        float wq_[4], wk_[4], wv_[4];
#pragma unroll
        for (int j = 0; j < 4; ++j) {
            const int d = d4 * 4 + j;
            wq_[j] = wq[(size_t)d * DKK];
            wk_[j] = wk[(size_t)d * DKK];
            wv_[j] = wv[(size_t)d * DKK];
        }
#pragma unroll
        for (int m = 0; m < 16; ++m) {
            const float4 a = *(const float4*)&rowbuf[m][d4 * 4];
            aq[m] += a.x * wq_[0] + a.y * wq_[1] + a.z * wq_[2] + a.w * wq_[3];
            ak[m] += a.x * wk_[0] + a.y * wk_[1] + a.z * wk_[2] + a.w * wk_[3];
            av[m] += a.x * wv_[0] + a.y * wv_[1] + a.z * wv_[2] + a.w * wv_[3];
        }
    }

    const float bq_ = bq[h * DKK + kk];
    const float bk_ = bk[h * DKK + kk];
    const float bv_ = bv[h * DKK + kk];
#pragma unroll
    for (int m = 0; m < 16; ++m) {
        const int r = r0 + m;
        const int b = r >> 12;            // r / S
        const int s = r & (SS - 1);       // r % S
        const size_t o = ((size_t)(b * HH + h) * SS + s) * DKK + kk;
        q[o] = aq[m] + bq_;
        k[o] = ak[m] + bk_;
        v[o] = av[m] + bv_;
    }
}

// ---------------------------------------------------------------------------
// K2: flash attention, fp32.  One q-row per thread, 256 q rows per block.
// K/V tiles of 128 staged in LDS; online softmax in base-2, groups of 8.
// Writes ctx in [B,S,H*DK] layout.
// ---------------------------------------------------------------------------
__global__ __launch_bounds__(256) void attn_k(
    const float* __restrict__ q, const float* __restrict__ k,
    const float* __restrict__ v, float* __restrict__ ctx)
{
    __shared__ float Kl[128][DKK];   // 16 KB
    __shared__ float Vl[128][DKK];   // 16 KB

    const int tid  = threadIdx.x;
    const int bh   = blockIdx.x;          // 0..15
    const int b    = bh >> 3;
    const int h    = bh & 7;
    const int spos = blockIdx.y * 256 + tid;

    // q row into registers, pre-scaled into log2 domain
    float qr[DKK];
    {
        const float4* qv = (const float4*)(q + ((size_t)bh * SS + spos) * DKK);
#pragma unroll
        for (int d4 = 0; d4 < 8; ++d4) {
            const float4 t = qv[d4];
            qr[d4 * 4 + 0] = t.x * SCALE2;
            qr[d4 * 4 + 1] = t.y * SCALE2;
            qr[d4 * 4 + 2] = t.z * SCALE2;
            qr[d4 * 4 + 3] = t.w * SCALE2;
        }
    }

    float m = -INFINITY, l = 0.f;
    float o[DKK];
#pragma unroll
    for (int d = 0; d < DKK; ++d) o[d] = 0.f;

    const float* kbase = k + (size_t)bh * SS * DKK;
    const float* vbase = v + (size_t)bh * SS * DKK;

    for (int t0 = 0; t0 < SS; t0 += 128) {
        __syncthreads();   // protect previous tile reads
        const float4* ks = (const float4*)(kbase + (size_t)t0 * DKK);
        const float4* vs = (const float4*)(vbase + (size_t)t0 * DKK);
        float4* kd = (float4*)&Kl[0][0];
        float4* vd = (float4*)&Vl[0][0];
#pragma unroll
        for (int i = 0; i < 4; ++i) {
            kd[i * 256 + tid] = ks[i * 256 + tid];
            vd[i * 256 + tid] = vs[i * 256 + tid];
        }
        __syncthreads();

        for (int g = 0; g < 16; ++g) {
            float sc[8] = {0.f,0.f,0.f,0.f,0.f,0.f,0.f,0.f};
#pragma unroll
            for (int d4 = 0; d4 < 8; ++d4) {
                const float q0 = qr[d4*4+0], q1 = qr[d4*4+1];
                const float q2 = qr[d4*4+2], q3 = qr[d4*4+3];
#pragma unroll
                for (int i = 0; i < 8; ++i) {
                    const float4 kv4 = *(const float4*)&Kl[g * 8 + i][d4 * 4];
                    sc[i] += q0 * kv4.x + q1 * kv4.y + q2 * kv4.z + q3 * kv4.w;
                }
            }
            const float mg = fmaxf(fmaxf(fmaxf(sc[0], sc[1]), fmaxf(sc[2], sc[3])),
                                   fmaxf(fmaxf(sc[4], sc[5]), fmaxf(sc[6], sc[7])));
            const float mn = fmaxf(m, mg);
            const float c  = exp2f(m - mn);
            float p[8];
            float ps = 0.f;
#pragma unroll
            for (int i = 0; i < 8; ++i) { p[i] = exp2f(sc[i] - mn); ps += p[i]; }
            l = l * c + ps;
            m = mn;
#pragma unroll
            for (int d4 = 0; d4 < 8; ++d4) {
                float o0 = o[d4*4+0] * c, o1 = o[d4*4+1] * c;
                float o2 = o[d4*4+2] * c, o3 = o[d4*4+3] * c;
#pragma unroll
                for (int i = 0; i < 8; ++i) {
                    const float4 vv = *(const float4*)&Vl[g * 8 + i][d4 * 4];
                    o0 += p[i] * vv.x; o1 += p[i] * vv.y;
                    o2 += p[i] * vv.z; o3 += p[i] * vv.w;
                }
                o[d4*4+0] = o0; o[d4*4+1] = o1; o[d4*4+2] = o2; o[d4*4+3] = o3;
            }
        }
    }

    const float inv = 1.0f / l;
    float4* cv = (float4*)(ctx + ((size_t)b * SS + spos) * (HH * DKK) + h * DKK);
#pragma unroll
    for (int d4 = 0; d4 < 8; ++d4)
        cv[d4] = make_float4(o[d4*4+0] * inv, o[d4*4+1] * inv,
                             o[d4*4+2] * inv, o[d4*4+3] * inv);
}

// ---------------------------------------------------------------------------
// K3/K4/K5: tiled fp32 GEMM  C[M,N] = A[M,K] @ W[K,N] (+bias, +residual/relu)
// BM=BN=64, BK=16, 256 threads, 4x4 register tile per thread.
// EPI 0: +bias +R (residual)      (Wo)
// EPI 1: relu(+bias)              (W1)
// EPI 2: +bias +R (residual)      (W2)
// ---------------------------------------------------------------------------
template <int EPI>
__global__ __launch_bounds__(256) void gemm64_k(
    const float* __restrict__ A, const float* __restrict__ W,
    const float* __restrict__ bias, const float* __restrict__ R,
    float* __restrict__ C, int K, int N)
{
    __shared__ float Al[16][68];   // padded, 272 B row stride (16B-aligned)
    __shared__ float Bl[16][64];

    const int tid = threadIdx.x;
    const int tx  = tid & 15;
    const int ty  = tid >> 4;
    const int m0  = blockIdx.y * 64;
    const int n0  = blockIdx.x * 64;

    const int ar  = tid >> 2;   // A stage: row 0..63
    const int ac4 = tid & 3;    // A stage: float4 chunk 0..3
    const int bk  = tid >> 4;   // W stage: k row 0..15
    const int bn4 = tid & 15;   // W stage: float4 chunk 0..15

    const float* Ap = A + (size_t)(m0 + ar) * K + ac4 * 4;
    const float* Wp = W + (size_t)bk * N + n0 + bn4 * 4;

    float acc[4][4];
#pragma unroll
    for (int i = 0; i < 4; ++i)
#pragma unroll
        for (int j = 0; j < 4; ++j) acc[i][j] = 0.f;

    for (int k0 = 0; k0 < K; k0 += 16) {
        const float4 avv = *(const float4*)(Ap + k0);
        const float4 wvv = *(const float4*)(Wp + (size_t)k0 * N);
        __syncthreads();
        Al[ac4 * 4 + 0][ar] = avv.x;
        Al[ac4 * 4 + 1][ar] = avv.y;
        Al[ac4 * 4 + 2][ar] = avv.z;
        Al[ac4 * 4 + 3][ar] = avv.w;
        *(float4*)&Bl[bk][bn4 * 4] = wvv;
        __syncthreads();
#pragma unroll
        for (int kk = 0; kk < 16; ++kk) {
            const float4 a4 = *(const float4*)&Al[kk][ty * 4];
            const float4 b4 = *(const float4*)&Bl[kk][tx * 4];
            const float a[4] = {a4.x, a4.y, a4.z, a4.w};
            const float bb[4] = {b4.x, b4.y, b4.z, b4.w};
#pragma unroll
            for (int i = 0; i < 4; ++i)
#pragma unroll
                for (int j = 0; j < 4; ++j) acc[i][j] += a[i] * bb[j];
        }
    }

    const int n = n0 + tx * 4;
    const float4 bv = *(const float4*)&bias[n];
#pragma unroll
    for (int i = 0; i < 4; ++i) {
        const size_t mrow = (size_t)(m0 + ty * 4 + i);
        float4 r;
        r.x = acc[i][0] + bv.x;
        r.y = acc[i][1] + bv.y;
        r.z = acc[i][2] + bv.z;
        r.w = acc[i][3] + bv.w;
        if constexpr (EPI == 0 || EPI == 2) {
            const float4 rv = *(const float4*)&R[mrow * N + n];
            r.x += rv.x; r.y += rv.y; r.z += rv.z; r.w += rv.w;
        }
        if constexpr (EPI == 1) {
            r.x = fmaxf(r.x, 0.f); r.y = fmaxf(r.y, 0.f);
            r.z = fmaxf(r.z, 0.f); r.w = fmaxf(r.w, 0.f);
        }
        *(float4*)&C[mrow * N + n] = r;
    }
}

// ---------------------------------------------------------------------------
// LayerNorm over rows of 256.  One block per row.  Safe in-place.
// ---------------------------------------------------------------------------
__global__ __launch_bounds__(256) void ln_k(
    const float* __restrict__ y, const float* __restrict__ g,
    const float* __restrict__ be, float* __restrict__ out)
{
    const int tid = threadIdx.x;
    const size_t r = blockIdx.x;
    const float val = y[r * DD + tid];
    float s1 = val, s2 = val * val;
#pragma unroll
    for (int i = 1; i < 64; i <<= 1) {
        s1 += __shfl_xor(s1, i, 64);
        s2 += __shfl_xor(s2, i, 64);
    }
    __shared__ float ps1[4], ps2[4];
    const int w = tid >> 6, lane = tid & 63;
    if (lane == 0) { ps1[w] = s1; ps2[w] = s2; }
    __syncthreads();
    const float t1 = ps1[0] + ps1[1] + ps1[2] + ps1[3];
    const float t2 = ps2[0] + ps2[1] + ps2[2] + ps2[3];
    const float mean = t1 * (1.f / DD);
    const float var  = t2 * (1.f / DD) - mean * mean;
    const float rs   = rsqrtf(var + 1e-5f);
    out[r * DD + tid] = (val - mean) * rs * g[tid] + be[tid];
}

// ---------------------------------------------------------------------------
extern "C" void kernel_launch(void* const* d_in, const int* in_sizes, int n_in,
                              void* d_out, int out_size, void* d_ws, size_t ws_size,
                              hipStream_t stream)
{
    const float* src  = (const float*)d_in[0];
    const float* Wq   = (const float*)d_in[1];
    const float* bq   = (const float*)d_in[2];
    const float* Wk   = (const float*)d_in[3];
    const float* bk   = (const float*)d_in[4];
    const float* Wv   = (const float*)d_in[5];
    const float* bv   = (const float*)d_in[6];
    const float* Wo   = (const float*)d_in[7];
    const float* bo   = (const float*)d_in[8];
    const float* ln1g = (const float*)d_in[9];
    const float* ln1b = (const float*)d_in[10];
    const float* W1   = (const float*)d_in[11];
    const float* b1   = (const float*)d_in[12];
    const float* W2   = (const float*)d_in[13];
    const float* b2   = (const float*)d_in[14];
    const float* ln2g = (const float*)d_in[15];
    const float* ln2b = (const float*)d_in[16];
    float* out = (float*)d_out;

    float* ws = (float*)d_ws;
    const size_t PROJ = (size_t)BB * HH * SS * DKK;   // 2M floats
    float* q   = ws + 0 * PROJ;
    float* k   = ws + 1 * PROJ;
    float* v   = ws + 2 * PROJ;
    float* ctx = ws + 3 * PROJ;
    float* y1  = ws + 4 * PROJ;          // attn GEMM out + src (pre-LN1)
    float* x   = ws + 5 * PROJ;          // post-LN1 (needed for FFN residual)
    float* hh  = ws + 0;                 // FFN hidden [8192,1024]; aliases
                                         // q/k/v/ctx which are dead by then

    // 1. QKV projection
    qkv_proj_k<<<BS / 16, 256, 0, stream>>>(src, Wq, bq, Wk, bk, Wv, bv, q, k, v);

    // 2. flash attention -> ctx [B,S,256]
    attn_k<<<dim3(BB * HH, SS / 256), 256, 0, stream>>>(q, k, v, ctx);

    // 3. ctx @ Wo + bo + src -> y1
    gemm64_k<0><<<dim3(DD / 64, BS / 64), 256, 0, stream>>>(ctx, Wo, bo, src, y1, DD, DD);

    // 4. LN1: y1 -> x
    ln_k<<<BS, DD, 0, stream>>>(y1, ln1g, ln1b, x);

    // 5. x @ W1 + b1, relu -> hh
    gemm64_k<1><<<dim3(DFFC / 64, BS / 64), 256, 0, stream>>>(x, W1, b1, nullptr, hh, DD, DFFC);

    // 6. hh @ W2 + b2 + x -> out (pre-LN2)
    gemm64_k<2><<<dim3(DD / 64, BS / 64), 256, 0, stream>>>(hh, W2, b2, x, out, DFFC, DD);

    // 7. LN2 in-place on out
    ln_k<<<BS, DD, 0, stream>>>(out, ln2g, ln2b, out);
}

// Round 4
// 488.099 us; speedup vs baseline: 3.4154x; 3.4154x over previous
//
#include <hip/hip_runtime.h>
#include <hip/hip_bf16.h>

// Problem constants
#define BB   2
#define SS   4096
#define DD   256
#define HH   8
#define DKK  32
#define DFFC 1024
#define BS   (BB*SS)          // 8192 rows

// softmax scale folded into q at projection time, log2 domain:
// 1/sqrt(32) * 1/ln(2)
#define SCALE2 (0.17677669529663689f * 1.4426950408889634f)

typedef float f32x4 __attribute__((ext_vector_type(4)));
typedef __bf16 bf16x8 __attribute__((ext_vector_type(8)));

static __device__ __forceinline__ unsigned short f2bf(float f) {
    union { float f; unsigned int u; } a; a.f = f;
    unsigned int u = a.u;
    u += 0x7fffu + ((u >> 16) & 1u);   // RNE (finite inputs only)
    return (unsigned short)(u >> 16);
}

// ---------------------------------------------------------------------------
// K1: QKV projection.  src[BS,256] x {Wq,Wk,Wv}[H,256,32] -> bf16 q,k,v
// [B,H,S,32].  q is pre-scaled by SCALE2 (softmax scale, log2 domain).
// ---------------------------------------------------------------------------
__global__ __launch_bounds__(256) void qkv_proj_k(
    const float* __restrict__ src,
    const float* __restrict__ Wq, const float* __restrict__ bq,
    const float* __restrict__ Wk, const float* __restrict__ bk,
    const float* __restrict__ Wv, const float* __restrict__ bv,
    unsigned short* __restrict__ q, unsigned short* __restrict__ k,
    unsigned short* __restrict__ v)
{
    __shared__ float rowbuf[16][DD];          // 16 KB
    const int tid = threadIdx.x;
    const int r0  = blockIdx.x * 16;

    const float4* sv = (const float4*)(src + (size_t)r0 * DD);
    float4* rb = (float4*)&rowbuf[0][0];
#pragma unroll
    for (int i = 0; i < 4; ++i) rb[i * 256 + tid] = sv[i * 256 + tid];
    __syncthreads();

    const int h  = tid >> 5;
    const int kk = tid & 31;
    const float* wq = Wq + (size_t)h * DD * DKK + kk;
    const float* wk = Wk + (size_t)h * DD * DKK + kk;
    const float* wv = Wv + (size_t)h * DD * DKK + kk;

    float aq[16], ak[16], av[16];
#pragma unroll
    for (int m = 0; m < 16; ++m) { aq[m] = 0.f; ak[m] = 0.f; av[m] = 0.f; }

    for (int d4 = 0; d4 < DD / 4; ++d4) {
        float wq_[4], wk_[4], wv_[4];
#pragma unroll
        for (int j = 0; j < 4; ++j) {
            const int d = d4 * 4 + j;
            wq_[j] = wq[(size_t)d * DKK];
            wk_[j] = wk[(size_t)d * DKK];
            wv_[j] = wv[(size_t)d * DKK];
        }
#pragma unroll
        for (int m = 0; m < 16; ++m) {
            const float4 a = *(const float4*)&rowbuf[m][d4 * 4];
            aq[m] += a.x * wq_[0] + a.y * wq_[1] + a.z * wq_[2] + a.w * wq_[3];
            ak[m] += a.x * wk_[0] + a.y * wk_[1] + a.z * wk_[2] + a.w * wk_[3];
            av[m] += a.x * wv_[0] + a.y * wv_[1] + a.z * wv_[2] + a.w * wv_[3];
        }
    }

    const float bq_ = bq[h * DKK + kk];
    const float bk_ = bk[h * DKK + kk];
    const float bv_ = bv[h * DKK + kk];
#pragma unroll
    for (int m = 0; m < 16; ++m) {
        const int r = r0 + m;
        const int b = r >> 12;            // r / S
        const int s = r & (SS - 1);       // r % S
        const size_t o = ((size_t)(b * HH + h) * SS + s) * DKK + kk;
        q[o] = f2bf((aq[m] + bq_) * SCALE2);
        k[o] = f2bf(ak[m] + bk_);
        v[o] = f2bf(av[m] + bv_);
    }
}

// ---------------------------------------------------------------------------
// K2: MFMA flash attention (bf16 operands, fp32 accum/softmax state).
// Block = 256 threads = 4 waves; each wave owns 16 q-rows; block = 64 q-rows.
// KV tile = 64 keys staged in LDS (K row-major padded, V transposed padded).
// mfma_f32_16x16x32_bf16:
//   A: lane holds A[row=l&15][k=(l>>4)*8+j]   (bf16x8, contiguous k)
//   B: lane holds B[k=(l>>4)*8+j][col=l&15]
//   D: reg r of lane l = D[(l>>4)*4+r][l&15]
// Grid: (BB*HH, SS/64) = 1024 blocks -> ~16 waves/CU.
// ---------------------------------------------------------------------------
#define RK 40   // K LDS row stride (bf16 elems) = 80 B
#define RV 72   // Vt/P LDS row stride (bf16 elems) = 144 B

__global__ __launch_bounds__(256) void attn_mfma_k(
    const unsigned short* __restrict__ qb, const unsigned short* __restrict__ kb,
    const unsigned short* __restrict__ vb, float* __restrict__ ctx)
{
    __shared__ unsigned short Kl[64 * RK];     // 5.0 KB
    __shared__ unsigned short Vt[32 * RV];     // 4.5 KB  (Vt[dv][t])
    __shared__ unsigned short Pl[4][16 * RV];  // 9.0 KB  (per-wave P[q][t])

    const int tid  = threadIdx.x;
    const int w    = tid >> 6;
    const int lane = tid & 63;
    const int lq   = lane & 15;
    const int lk   = lane >> 4;       // 0..3
    const int bh   = blockIdx.x;
    const int b    = bh >> 3;
    const int h    = bh & 7;
    const int q0   = blockIdx.y * 64;

    // staging roles
    const int ktrow = tid >> 2, ktc = tid & 3;   // K: 64 rows x 4 chunks
    const int vtrow = tid & 63, vdc = tid >> 6;  // V: 64 rows x 4 dv-chunks

    const unsigned short* kg = kb + (size_t)bh * SS * DKK;
    const unsigned short* vg = vb + (size_t)bh * SS * DKK;

    union U16 { int4 i; bf16x8 b; unsigned short s[8]; };

    // Q fragment (row-major A-frag), loaded once
    U16 uq;
    uq.i = *(const int4*)(qb + ((size_t)bh * SS + q0 + w * 16 + lq) * DKK + lk * 8);
    const bf16x8 aq = uq.b;

    float m_[4], l_[4];
    f32x4 o0 = {0.f, 0.f, 0.f, 0.f};
    f32x4 o1 = {0.f, 0.f, 0.f, 0.f};
#pragma unroll
    for (int r = 0; r < 4; ++r) { m_[r] = -INFINITY; l_[r] = 0.f; }

    for (int t0 = 0; t0 < SS; t0 += 64) {
        __syncthreads();   // protect LDS reuse from previous iteration
        // stage K tile: [64][32] bf16, padded rows
        *(int4*)&Kl[ktrow * RK + ktc * 8] =
            *(const int4*)(kg + (size_t)(t0 + ktrow) * DKK + ktc * 8);
        // stage V tile transposed: Vt[dv][t]
        U16 uv;
        uv.i = *(const int4*)(vg + (size_t)(t0 + vtrow) * DKK + vdc * 8);
#pragma unroll
        for (int j = 0; j < 8; ++j) Vt[(vdc * 8 + j) * RV + vtrow] = uv.s[j];
        __syncthreads();

        // QK^T: 4 mfma -> S[16q][64t] (log2 domain, q pre-scaled)
        f32x4 acc[4];
#pragma unroll
        for (int g = 0; g < 4; ++g) {
            const bf16x8 bk_ = *(const bf16x8*)&Kl[(g * 16 + lq) * RK + lk * 8];
            acc[g] = __builtin_amdgcn_mfma_f32_16x16x32_bf16(
                aq, bk_, (f32x4){0.f, 0.f, 0.f, 0.f}, 0, 0, 0);
        }

        // online softmax; only row-max needs cross-lane reduce (over 16 cols)
#pragma unroll
        for (int r = 0; r < 4; ++r) {
            float rm = fmaxf(fmaxf(acc[0][r], acc[1][r]),
                             fmaxf(acc[2][r], acc[3][r]));
            rm = fmaxf(rm, __shfl_xor(rm, 1));
            rm = fmaxf(rm, __shfl_xor(rm, 2));
            rm = fmaxf(rm, __shfl_xor(rm, 4));
            rm = fmaxf(rm, __shfl_xor(rm, 8));
            const float mn = fmaxf(m_[r], rm);
            const float c  = exp2f(m_[r] - mn);
            m_[r] = mn;
            const float p0 = exp2f(acc[0][r] - mn);
            const float p1 = exp2f(acc[1][r] - mn);
            const float p2 = exp2f(acc[2][r] - mn);
            const float p3 = exp2f(acc[3][r] - mn);
            const int prow = (lk * 4 + r) * RV;
            Pl[w][prow +  0 + lq] = f2bf(p0);
            Pl[w][prow + 16 + lq] = f2bf(p1);
            Pl[w][prow + 32 + lq] = f2bf(p2);
            Pl[w][prow + 48 + lq] = f2bf(p3);
            l_[r] = l_[r] * c + (p0 + p1 + p2 + p3);   // per-lane partial sum
            o0[r] *= c;
            o1[r] *= c;
        }

        // PV: O[16q][32dv] += P[16q][64t] * V[64t][32dv]
#pragma unroll
        for (int c2 = 0; c2 < 2; ++c2) {
            const bf16x8 pa = *(const bf16x8*)&Pl[w][lq * RV + c2 * 32 + lk * 8];
            const bf16x8 v0 = *(const bf16x8*)&Vt[(lq)      * RV + c2 * 32 + lk * 8];
            o0 = __builtin_amdgcn_mfma_f32_16x16x32_bf16(pa, v0, o0, 0, 0, 0);
            const bf16x8 v1 = *(const bf16x8*)&Vt[(16 + lq) * RV + c2 * 32 + lk * 8];
            o1 = __builtin_amdgcn_mfma_f32_16x16x32_bf16(pa, v1, o1, 0, 0, 0);
        }
    }

    // epilogue: reduce per-lane partial row sums across the 16 cols, divide
#pragma unroll
    for (int r = 0; r < 4; ++r) {
        float ls = l_[r];
        ls += __shfl_xor(ls, 1);
        ls += __shfl_xor(ls, 2);
        ls += __shfl_xor(ls, 4);
        ls += __shfl_xor(ls, 8);
        const float inv = 1.0f / ls;
        const size_t row = (size_t)b * SS + q0 + w * 16 + lk * 4 + r;
        float* cp = ctx + row * (HH * DKK) + h * DKK;
        cp[lq]      = o0[r] * inv;
        cp[16 + lq] = o1[r] * inv;
    }
}

// ---------------------------------------------------------------------------
// K3/K4/K5: tiled fp32 GEMM  C[M,N] = A[M,K] @ W[K,N] (+bias, +residual/relu)
// ---------------------------------------------------------------------------
template <int EPI>
__global__ __launch_bounds__(256) void gemm64_k(
    const float* __restrict__ A, const float* __restrict__ W,
    const float* __restrict__ bias, const float* __restrict__ R,
    float* __restrict__ C, int K, int N)
{
    __shared__ float Al[16][68];
    __shared__ float Bl[16][64];

    const int tid = threadIdx.x;
    const int tx  = tid & 15;
    const int ty  = tid >> 4;
    const int m0  = blockIdx.y * 64;
    const int n0  = blockIdx.x * 64;

    const int ar  = tid >> 2;
    const int ac4 = tid & 3;
    const int bk  = tid >> 4;
    const int bn4 = tid & 15;

    const float* Ap = A + (size_t)(m0 + ar) * K + ac4 * 4;
    const float* Wp = W + (size_t)bk * N + n0 + bn4 * 4;

    float acc[4][4];
#pragma unroll
    for (int i = 0; i < 4; ++i)
#pragma unroll
        for (int j = 0; j < 4; ++j) acc[i][j] = 0.f;

    for (int k0 = 0; k0 < K; k0 += 16) {
        const float4 avv = *(const float4*)(Ap + k0);
        const float4 wvv = *(const float4*)(Wp + (size_t)k0 * N);
        __syncthreads();
        Al[ac4 * 4 + 0][ar] = avv.x;
        Al[ac4 * 4 + 1][ar] = avv.y;
        Al[ac4 * 4 + 2][ar] = avv.z;
        Al[ac4 * 4 + 3][ar] = avv.w;
        *(float4*)&Bl[bk][bn4 * 4] = wvv;
        __syncthreads();
#pragma unroll
        for (int kk = 0; kk < 16; ++kk) {
            const float4 a4 = *(const float4*)&Al[kk][ty * 4];
            const float4 b4 = *(const float4*)&Bl[kk][tx * 4];
            const float a[4] = {a4.x, a4.y, a4.z, a4.w};
            const float bb[4] = {b4.x, b4.y, b4.z, b4.w};
#pragma unroll
            for (int i = 0; i < 4; ++i)
#pragma unroll
                for (int j = 0; j < 4; ++j) acc[i][j] += a[i] * bb[j];
        }
    }

    const int n = n0 + tx * 4;
    const float4 bv = *(const float4*)&bias[n];
#pragma unroll
    for (int i = 0; i < 4; ++i) {
        const size_t mrow = (size_t)(m0 + ty * 4 + i);
        float4 r;
        r.x = acc[i][0] + bv.x;
        r.y = acc[i][1] + bv.y;
        r.z = acc[i][2] + bv.z;
        r.w = acc[i][3] + bv.w;
        if constexpr (EPI == 0 || EPI == 2) {
            const float4 rv = *(const float4*)&R[mrow * N + n];
            r.x += rv.x; r.y += rv.y; r.z += rv.z; r.w += rv.w;
        }
        if constexpr (EPI == 1) {
            r.x = fmaxf(r.x, 0.f); r.y = fmaxf(r.y, 0.f);
            r.z = fmaxf(r.z, 0.f); r.w = fmaxf(r.w, 0.f);
        }
        *(float4*)&C[mrow * N + n] = r;
    }
}

// ---------------------------------------------------------------------------
// LayerNorm over rows of 256.  One block per row.  Safe in-place.
// ---------------------------------------------------------------------------
__global__ __launch_bounds__(256) void ln_k(
    const float* __restrict__ y, const float* __restrict__ g,
    const float* __restrict__ be, float* __restrict__ out)
{
    const int tid = threadIdx.x;
    const size_t r = blockIdx.x;
    const float val = y[r * DD + tid];
    float s1 = val, s2 = val * val;
#pragma unroll
    for (int i = 1; i < 64; i <<= 1) {
        s1 += __shfl_xor(s1, i, 64);
        s2 += __shfl_xor(s2, i, 64);
    }
    __shared__ float ps1[4], ps2[4];
    const int w = tid >> 6, lane = tid & 63;
    if (lane == 0) { ps1[w] = s1; ps2[w] = s2; }
    __syncthreads();
    const float t1 = ps1[0] + ps1[1] + ps1[2] + ps1[3];
    const float t2 = ps2[0] + ps2[1] + ps2[2] + ps2[3];
    const float mean = t1 * (1.f / DD);
    const float var  = t2 * (1.f / DD) - mean * mean;
    const float rs   = rsqrtf(var + 1e-5f);
    out[r * DD + tid] = (val - mean) * rs * g[tid] + be[tid];
}

// ---------------------------------------------------------------------------
extern "C" void kernel_launch(void* const* d_in, const int* in_sizes, int n_in,
                              void* d_out, int out_size, void* d_ws, size_t ws_size,
                              hipStream_t stream)
{
    const float* src  = (const float*)d_in[0];
    const float* Wq   = (const float*)d_in[1];
    const float* bq   = (const float*)d_in[2];
    const float* Wk   = (const float*)d_in[3];
    const float* bk   = (const float*)d_in[4];
    const float* Wv   = (const float*)d_in[5];
    const float* bv   = (const float*)d_in[6];
    const float* Wo   = (const float*)d_in[7];
    const float* bo   = (const float*)d_in[8];
    const float* ln1g = (const float*)d_in[9];
    const float* ln1b = (const float*)d_in[10];
    const float* W1   = (const float*)d_in[11];
    const float* b1   = (const float*)d_in[12];
    const float* W2   = (const float*)d_in[13];
    const float* b2   = (const float*)d_in[14];
    const float* ln2g = (const float*)d_in[15];
    const float* ln2b = (const float*)d_in[16];
    float* out = (float*)d_out;

    // Workspace layout (bytes):
    //   [0,8M)    x    (post-LN1, fp32, survives through FFN)
    //   [8M,12M)  qb   (bf16)   [12M,16M) kb   [16M,20M) vb
    //   [20M,28M) ctx  (fp32)   [28M,36M) y1   (fp32)
    //   hh (fp32, 32MB) at [8M,40M) -- aliases qb/kb/vb/ctx/y1, all dead by FFN
    char* wsb = (char*)d_ws;
    float*          x   = (float*)(wsb);
    unsigned short* qb  = (unsigned short*)(wsb + (size_t)8  * 1024 * 1024);
    unsigned short* kb2 = (unsigned short*)(wsb + (size_t)12 * 1024 * 1024);
    unsigned short* vb2 = (unsigned short*)(wsb + (size_t)16 * 1024 * 1024);
    float*          ctx = (float*)(wsb + (size_t)20 * 1024 * 1024);
    float*          y1  = (float*)(wsb + (size_t)28 * 1024 * 1024);
    float*          hh  = (float*)(wsb + (size_t)8  * 1024 * 1024);

    // 1. QKV projection (bf16 out, q pre-scaled)
    qkv_proj_k<<<BS / 16, 256, 0, stream>>>(src, Wq, bq, Wk, bk, Wv, bv, qb, kb2, vb2);

    // 2. MFMA flash attention -> ctx [B,S,256] fp32
    attn_mfma_k<<<dim3(BB * HH, SS / 64), 256, 0, stream>>>(qb, kb2, vb2, ctx);

    // 3. ctx @ Wo + bo + src -> y1
    gemm64_k<0><<<dim3(DD / 64, BS / 64), 256, 0, stream>>>(ctx, Wo, bo, src, y1, DD, DD);

    // 4. LN1: y1 -> x
    ln_k<<<BS, DD, 0, stream>>>(y1, ln1g, ln1b, x);

    // 5. x @ W1 + b1, relu -> hh
    gemm64_k<1><<<dim3(DFFC / 64, BS / 64), 256, 0, stream>>>(x, W1, b1, nullptr, hh, DD, DFFC);

    // 6. hh @ W2 + b2 + x -> out (pre-LN2)
    gemm64_k<2><<<dim3(DD / 64, BS / 64), 256, 0, stream>>>(hh, W2, b2, x, out, DFFC, DD);

    // 7. LN2 in-place on out
    ln_k<<<BS, DD, 0, stream>>>(out, ln2g, ln2b, out);
}

// Round 5
// 362.013 us; speedup vs baseline: 4.6050x; 1.3483x over previous
//
#include <hip/hip_runtime.h>
#include <hip/hip_bf16.h>

// Problem constants
#define BB   2
#define SS   4096
#define DD   256
#define HH   8
#define DKK  32
#define DFFC 1024
#define BS   (BB*SS)          // 8192 rows
#define MB   (1024*1024)

// softmax scale folded into q, log2 domain: 1/sqrt(32) * 1/ln(2)
#define SCALE2 (0.17677669529663689f * 1.4426950408889634f)

typedef float f32x4 __attribute__((ext_vector_type(4)));
typedef __bf16 bf16x8 __attribute__((ext_vector_type(8)));

static __device__ __forceinline__ unsigned short f2bf(float f) {
    union { float f; unsigned int u; } a; a.f = f;
    unsigned int u = a.u;
    u += 0x7fffu + ((u >> 16) & 1u);   // RNE (finite inputs only)
    return (unsigned short)(u >> 16);
}

// ---------------------------------------------------------------------------
// K0: one-shot conversions (runs every launch; graph-safe).
//  - srcb  = bf16(src)                            [8192*256]
//  - Wqkv_t[768][256] bf16: c=(which,h,kk), from Wq/Wk/Wv[h][d][kk]
//  - Wo_t  [256][256]  bf16 = Wo^T
//  - W1_t  [1024][256] bf16 = W1^T
//  - W2_t  [256][1024] bf16 = W2^T
//  - bqkv  [768] f32 = concat(bq,bk,bv)
// ---------------------------------------------------------------------------
__global__ __launch_bounds__(256) void convert_k(
    const float* __restrict__ src,
    const float* __restrict__ Wq, const float* __restrict__ Wk,
    const float* __restrict__ Wv, const float* __restrict__ Wo,
    const float* __restrict__ W1, const float* __restrict__ W2,
    const float* __restrict__ bq, const float* __restrict__ bk,
    const float* __restrict__ bv,
    unsigned short* __restrict__ srcb, unsigned short* __restrict__ Wqkv_t,
    unsigned short* __restrict__ Wo_t, unsigned short* __restrict__ W1_t,
    unsigned short* __restrict__ W2_t, float* __restrict__ bqkv)
{
    int idx = blockIdx.x * 256 + threadIdx.x;
    if (idx < 2097152) { srcb[idx] = f2bf(src[idx]); return; }
    int i = idx - 2097152;
    if (i < 196608) {                       // Wqkv_t [768][256]
        const int c = i >> 8, d = i & 255;
        const int which = c >> 8, h = (c >> 5) & 7, kk = c & 31;
        const float* W = which == 0 ? Wq : which == 1 ? Wk : Wv;
        Wqkv_t[i] = f2bf(W[h * 8192 + d * 32 + kk]);
        return;
    }
    i -= 196608;
    if (i < 65536) {                        // Wo_t [256][256]
        const int n = i >> 8, k2 = i & 255;
        Wo_t[i] = f2bf(Wo[k2 * 256 + n]);
        return;
    }
    i -= 65536;
    if (i < 262144) {                       // W1_t [1024][256]
        const int n = i >> 8, k2 = i & 255;
        W1_t[i] = f2bf(W1[k2 * 1024 + n]);
        return;
    }
    i -= 262144;
    if (i < 262144) {                       // W2_t [256][1024]
        const int n = i >> 10, k2 = i & 1023;
        W2_t[i] = f2bf(W2[k2 * 256 + n]);
        return;
    }
    i -= 262144;
    if (i < 768)
        bqkv[i] = (i < 256) ? bq[i] : (i < 512) ? bk[i - 256] : bv[i - 512];
}

// ---------------------------------------------------------------------------
// K1: bf16 MFMA GEMM.  C[M,N] = A[M,K] @ Bt[N,K]^T (+bias, epilogue variants)
// BM=128, BN=64, BK=32; 256 threads = 4 waves (2x2), wave tile 64x32.
// mfma_f32_16x16x32_bf16 frags:
//   A: lane holds A[row=l&15][k=(l>>4)*8+j]
//   B: lane holds B[k=(l>>4)*8+j][col=l&15]  (= Bt[col][k], k contiguous)
//   D: reg r = D[row=(l>>4)*4+r][col=l&15]
// EPI 0: fp32 out = acc + bias + Rres
// EPI 1: bf16 out = relu(acc + bias)
// EPI 2: qkv scatter: bf16 out to qkv[which][B,H,S,32], q scaled by SCALE2
// ---------------------------------------------------------------------------
#define LDA 36   // padded LDS row stride (shorts) = 72 B

template <int EPI, int K>
__global__ __launch_bounds__(256) void mfma_gemm_k(
    const unsigned short* __restrict__ A,
    const unsigned short* __restrict__ Bt,
    const float* __restrict__ bias,
    const float* __restrict__ Rres,
    void* __restrict__ Cout, int N)
{
    __shared__ unsigned short Al[128 * LDA];   // 9216 B
    __shared__ unsigned short Bl[64 * LDA];    // 4608 B

    const int tid  = threadIdx.x;
    const int w    = tid >> 6, lane = tid & 63;
    const int lq   = lane & 15, lk = lane >> 4;
    const int wr   = w >> 1,   wc = w & 1;
    const int m0   = blockIdx.y * 128, n0 = blockIdx.x * 64;

    // staging roles
    const int arow = tid >> 1, ac = (tid & 1) * 16;   // A: 128 rows x 2 halves
    const int brow = tid >> 2, bc = (tid & 3) * 8;    // B: 64 rows x 4 chunks
    const unsigned short* Ap = A  + (size_t)(m0 + arow) * K + ac;
    const unsigned short* Bp = Bt + (size_t)(n0 + brow) * K + bc;

    f32x4 acc[4][2];
#pragma unroll
    for (int mi = 0; mi < 4; ++mi)
#pragma unroll
        for (int ni = 0; ni < 2; ++ni) acc[mi][ni] = (f32x4){0.f, 0.f, 0.f, 0.f};

    for (int k0 = 0; k0 < K; k0 += 32) {
        const int4 a0 = *(const int4*)(Ap + k0);
        const int4 a1 = *(const int4*)(Ap + k0 + 8);
        const int4 b0 = *(const int4*)(Bp + k0);
        __syncthreads();
        *(int4*)&Al[arow * LDA + ac]     = a0;
        *(int4*)&Al[arow * LDA + ac + 8] = a1;
        *(int4*)&Bl[brow * LDA + bc]     = b0;
        __syncthreads();

        bf16x8 bfrag[2];
#pragma unroll
        for (int ni = 0; ni < 2; ++ni)
            bfrag[ni] = *(const bf16x8*)&Bl[(wc * 32 + ni * 16 + lq) * LDA + lk * 8];
#pragma unroll
        for (int mi = 0; mi < 4; ++mi) {
            const bf16x8 afrag =
                *(const bf16x8*)&Al[(wr * 64 + mi * 16 + lq) * LDA + lk * 8];
#pragma unroll
            for (int ni = 0; ni < 2; ++ni)
                acc[mi][ni] = __builtin_amdgcn_mfma_f32_16x16x32_bf16(
                    afrag, bfrag[ni], acc[mi][ni], 0, 0, 0);
        }
    }

    // epilogue
#pragma unroll
    for (int ni = 0; ni < 2; ++ni) {
        const int col = n0 + wc * 32 + ni * 16 + lq;
        const float bv_ = bias[col];
#pragma unroll
        for (int mi = 0; mi < 4; ++mi) {
#pragma unroll
            for (int r = 0; r < 4; ++r) {
                const int row = m0 + wr * 64 + mi * 16 + lk * 4 + r;
                float val = acc[mi][ni][r] + bv_;
                if constexpr (EPI == 0) {
                    ((float*)Cout)[(size_t)row * N + col] =
                        val + Rres[(size_t)row * N + col];
                } else if constexpr (EPI == 1) {
                    ((unsigned short*)Cout)[(size_t)row * N + col] =
                        f2bf(fmaxf(val, 0.f));
                } else {
                    const int which = col >> 8, h = (col >> 5) & 7, kk = col & 31;
                    if (which == 0) val *= SCALE2;
                    const int b = row >> 12, s = row & (SS - 1);
                    ((unsigned short*)Cout)[(size_t)which * 2097152 +
                        ((size_t)(b * 8 + h) * SS + s) * 32 + kk] = f2bf(val);
                }
            }
        }
    }
}

// ---------------------------------------------------------------------------
// K2: MFMA flash attention (bf16 operands, fp32 accum/softmax state).
// Block = 4 waves; wave owns 16 q-rows; KV tile 64 in LDS. Output bf16 ctx.
// RV=74 (148 B rows): PV-read bank start = 5*lq+4*lk mod 32 -> <=2-way.
// ---------------------------------------------------------------------------
#define RK 40   // K LDS row stride (shorts) = 80 B
#define RV 74   // Vt/P LDS row stride (shorts) = 148 B

__global__ __launch_bounds__(256) void attn_mfma_k(
    const unsigned short* __restrict__ qb, const unsigned short* __restrict__ kb,
    const unsigned short* __restrict__ vb, unsigned short* __restrict__ ctxb)
{
    __shared__ unsigned short Kl[64 * RK];     // 5.0 KB
    __shared__ unsigned short Vt[32 * RV];     // 4.6 KB  (Vt[dv][t])
    __shared__ unsigned short Pl[4][16 * RV];  // 9.3 KB  (per-wave P[q][t])

    const int tid  = threadIdx.x;
    const int w    = tid >> 6;
    const int lane = tid & 63;
    const int lq   = lane & 15;
    const int lk   = lane >> 4;
    const int bh   = blockIdx.x;
    const int b    = bh >> 3;
    const int h    = bh & 7;
    const int q0   = blockIdx.y * 64;

    const int ktrow = tid >> 2, ktc = tid & 3;
    const int vtrow = tid & 63, vdc = tid >> 6;

    const unsigned short* kg = kb + (size_t)bh * SS * DKK;
    const unsigned short* vg = vb + (size_t)bh * SS * DKK;

    union U16 { int4 i; bf16x8 b; unsigned short s[8]; };

    U16 uq;
    uq.i = *(const int4*)(qb + ((size_t)bh * SS + q0 + w * 16 + lq) * DKK + lk * 8);
    const bf16x8 aq = uq.b;

    float m_[4], l_[4];
    f32x4 o0 = {0.f, 0.f, 0.f, 0.f};
    f32x4 o1 = {0.f, 0.f, 0.f, 0.f};
#pragma unroll
    for (int r = 0; r < 4; ++r) { m_[r] = -INFINITY; l_[r] = 0.f; }

    for (int t0 = 0; t0 < SS; t0 += 64) {
        __syncthreads();
        *(int4*)&Kl[ktrow * RK + ktc * 8] =
            *(const int4*)(kg + (size_t)(t0 + ktrow) * DKK + ktc * 8);
        U16 uv;
        uv.i = *(const int4*)(vg + (size_t)(t0 + vtrow) * DKK + vdc * 8);
#pragma unroll
        for (int j = 0; j < 8; ++j) Vt[(vdc * 8 + j) * RV + vtrow] = uv.s[j];
        __syncthreads();

        f32x4 acc[4];
#pragma unroll
        for (int g = 0; g < 4; ++g) {
            const bf16x8 bk_ = *(const bf16x8*)&Kl[(g * 16 + lq) * RK + lk * 8];
            acc[g] = __builtin_amdgcn_mfma_f32_16x16x32_bf16(
                aq, bk_, (f32x4){0.f, 0.f, 0.f, 0.f}, 0, 0, 0);
        }

#pragma unroll
        for (int r = 0; r < 4; ++r) {
            float rm = fmaxf(fmaxf(acc[0][r], acc[1][r]),
                             fmaxf(acc[2][r], acc[3][r]));
            rm = fmaxf(rm, __shfl_xor(rm, 1));
            rm = fmaxf(rm, __shfl_xor(rm, 2));
            rm = fmaxf(rm, __shfl_xor(rm, 4));
            rm = fmaxf(rm, __shfl_xor(rm, 8));
            const float mn = fmaxf(m_[r], rm);
            const float c  = exp2f(m_[r] - mn);
            m_[r] = mn;
            const float p0 = exp2f(acc[0][r] - mn);
            const float p1 = exp2f(acc[1][r] - mn);
            const float p2 = exp2f(acc[2][r] - mn);
            const float p3 = exp2f(acc[3][r] - mn);
            const int prow = (lk * 4 + r) * RV;
            Pl[w][prow +  0 + lq] = f2bf(p0);
            Pl[w][prow + 16 + lq] = f2bf(p1);
            Pl[w][prow + 32 + lq] = f2bf(p2);
            Pl[w][prow + 48 + lq] = f2bf(p3);
            l_[r] = l_[r] * c + (p0 + p1 + p2 + p3);
            o0[r] *= c;
            o1[r] *= c;
        }

#pragma unroll
        for (int c2 = 0; c2 < 2; ++c2) {
            const bf16x8 pa = *(const bf16x8*)&Pl[w][lq * RV + c2 * 32 + lk * 8];
            const bf16x8 v0 = *(const bf16x8*)&Vt[(lq)      * RV + c2 * 32 + lk * 8];
            o0 = __builtin_amdgcn_mfma_f32_16x16x32_bf16(pa, v0, o0, 0, 0, 0);
            const bf16x8 v1 = *(const bf16x8*)&Vt[(16 + lq) * RV + c2 * 32 + lk * 8];
            o1 = __builtin_amdgcn_mfma_f32_16x16x32_bf16(pa, v1, o1, 0, 0, 0);
        }
    }

#pragma unroll
    for (int r = 0; r < 4; ++r) {
        float ls = l_[r];
        ls += __shfl_xor(ls, 1);
        ls += __shfl_xor(ls, 2);
        ls += __shfl_xor(ls, 4);
        ls += __shfl_xor(ls, 8);
        const float inv = 1.0f / ls;
        const size_t row = (size_t)b * SS + q0 + w * 16 + lk * 4 + r;
        unsigned short* cp = ctxb + row * (HH * DKK) + h * DKK;
        cp[lq]      = f2bf(o0[r] * inv);
        cp[16 + lq] = f2bf(o1[r] * inv);
    }
}

// ---------------------------------------------------------------------------
// K3: LayerNorm rows of 256; optional bf16 secondary output.
// ---------------------------------------------------------------------------
__global__ __launch_bounds__(256) void ln_k(
    const float* __restrict__ y, const float* __restrict__ g,
    const float* __restrict__ be, float* __restrict__ out,
    unsigned short* __restrict__ outb)
{
    const int tid = threadIdx.x;
    const size_t r = blockIdx.x;
    const float val = y[r * DD + tid];
    float s1 = val, s2 = val * val;
#pragma unroll
    for (int i = 1; i < 64; i <<= 1) {
        s1 += __shfl_xor(s1, i, 64);
        s2 += __shfl_xor(s2, i, 64);
    }
    __shared__ float ps1[4], ps2[4];
    const int w = tid >> 6, lane = tid & 63;
    if (lane == 0) { ps1[w] = s1; ps2[w] = s2; }
    __syncthreads();
    const float t1 = ps1[0] + ps1[1] + ps1[2] + ps1[3];
    const float t2 = ps2[0] + ps2[1] + ps2[2] + ps2[3];
    const float mean = t1 * (1.f / DD);
    const float var  = t2 * (1.f / DD) - mean * mean;
    const float rs   = rsqrtf(var + 1e-5f);
    const float res  = (val - mean) * rs * g[tid] + be[tid];
    out[r * DD + tid] = res;
    if (outb) outb[r * DD + tid] = f2bf(res);
}

// ---------------------------------------------------------------------------
extern "C" void kernel_launch(void* const* d_in, const int* in_sizes, int n_in,
                              void* d_out, int out_size, void* d_ws, size_t ws_size,
                              hipStream_t stream)
{
    const float* src  = (const float*)d_in[0];
    const float* Wq   = (const float*)d_in[1];
    const float* bq   = (const float*)d_in[2];
    const float* Wk   = (const float*)d_in[3];
    const float* bk   = (const float*)d_in[4];
    const float* Wv   = (const float*)d_in[5];
    const float* bv   = (const float*)d_in[6];
    const float* Wo   = (const float*)d_in[7];
    const float* bo   = (const float*)d_in[8];
    const float* ln1g = (const float*)d_in[9];
    const float* ln1b = (const float*)d_in[10];
    const float* W1   = (const float*)d_in[11];
    const float* b1   = (const float*)d_in[12];
    const float* W2   = (const float*)d_in[13];
    const float* b2   = (const float*)d_in[14];
    const float* ln2g = (const float*)d_in[15];
    const float* ln2b = (const float*)d_in[16];
    float* out = (float*)d_out;

    // Workspace (42 MB):
    //  [0,8M)   x fp32          [8M,12M)  xb bf16
    //  [12M,16M) srcb bf16      [16M,28M) qb/kb/vb bf16 (4 MB each)
    //  [28M,32M) ctxb bf16      [32M,40M) y1 fp32
    //  hh bf16 16MB = [12M,28M) (aliases srcb+qkv, dead by FFN)
    //  [40M,...) bf16 weights + bqkv
    char* wsb = (char*)d_ws;
    float*          x     = (float*)(wsb);
    unsigned short* xb    = (unsigned short*)(wsb + (size_t) 8 * MB);
    unsigned short* srcb  = (unsigned short*)(wsb + (size_t)12 * MB);
    unsigned short* qb    = (unsigned short*)(wsb + (size_t)16 * MB);
    unsigned short* kb2   = (unsigned short*)(wsb + (size_t)20 * MB);
    unsigned short* vb2   = (unsigned short*)(wsb + (size_t)24 * MB);
    unsigned short* ctxb  = (unsigned short*)(wsb + (size_t)28 * MB);
    float*          y1    = (float*)(wsb + (size_t)32 * MB);
    unsigned short* hh    = (unsigned short*)(wsb + (size_t)12 * MB);
    unsigned short* Wqkv_t= (unsigned short*)(wsb + (size_t)40 * MB);
    unsigned short* Wo_t  = (unsigned short*)(wsb + (size_t)40 * MB + 384 * 1024);
    unsigned short* W1_t  = (unsigned short*)(wsb + (size_t)40 * MB + 512 * 1024);
    unsigned short* W2_t  = (unsigned short*)(wsb + (size_t)40 * MB + 1024 * 1024);
    float*          bqkv  = (float*)(wsb + (size_t)40 * MB + 1536 * 1024);

    // 0. conversions (2,884,352 work items)
    convert_k<<<11267, 256, 0, stream>>>(src, Wq, Wk, Wv, Wo, W1, W2, bq, bk, bv,
                                         srcb, Wqkv_t, Wo_t, W1_t, W2_t, bqkv);

    // 1. QKV: srcb @ Wqkv_t^T -> qb/kb/vb (scatter epilogue, q scaled)
    mfma_gemm_k<2, DD><<<dim3(12, 64), 256, 0, stream>>>(
        srcb, Wqkv_t, bqkv, nullptr, qb, 768);

    // 2. flash attention -> ctxb bf16 [B,S,256]
    attn_mfma_k<<<dim3(BB * HH, SS / 64), 256, 0, stream>>>(qb, kb2, vb2, ctxb);

    // 3. ctxb @ Wo_t^T + bo + src -> y1 fp32
    mfma_gemm_k<0, DD><<<dim3(4, 64), 256, 0, stream>>>(
        ctxb, Wo_t, bo, src, y1, DD);

    // 4. LN1: y1 -> x fp32 + xb bf16
    ln_k<<<BS, DD, 0, stream>>>(y1, ln1g, ln1b, x, xb);

    // 5. xb @ W1_t^T + b1, relu -> hh bf16
    mfma_gemm_k<1, DD><<<dim3(16, 64), 256, 0, stream>>>(
        xb, W1_t, b1, nullptr, hh, DFFC);

    // 6. hh @ W2_t^T + b2 + x -> out fp32
    mfma_gemm_k<0, DFFC><<<dim3(4, 64), 256, 0, stream>>>(
        hh, W2_t, b2, x, out, DD);

    // 7. LN2 in place
    ln_k<<<BS, DD, 0, stream>>>(out, ln2g, ln2b, out, nullptr);
}

// Round 7
// 301.016 us; speedup vs baseline: 5.5381x; 1.2026x over previous
//
#include <hip/hip_runtime.h>
#include <hip/hip_bf16.h>

// Problem constants
#define BB   2
#define SS   4096
#define DD   256
#define HH   8
#define DKK  32
#define DFFC 1024
#define BS   (BB*SS)          // 8192 rows
#define MB   (1024*1024)

// softmax scale folded into q, log2 domain: 1/sqrt(32) * 1/ln(2)
#define SCALE2 (0.17677669529663689f * 1.4426950408889634f)

typedef float f32x4 __attribute__((ext_vector_type(4)));
typedef __bf16 bf16x8 __attribute__((ext_vector_type(8)));

static __device__ __forceinline__ unsigned short f2bf(float f) {
    union { float f; unsigned int u; } a; a.f = f;
    unsigned int u = a.u;
    u += 0x7fffu + ((u >> 16) & 1u);   // RNE (finite inputs only)
    return (unsigned short)(u >> 16);
}

// ---------------------------------------------------------------------------
// K0: one-shot conversions (runs every launch; graph-safe).
// ---------------------------------------------------------------------------
__global__ __launch_bounds__(256) void convert_k(
    const float* __restrict__ src,
    const float* __restrict__ Wq, const float* __restrict__ Wk,
    const float* __restrict__ Wv, const float* __restrict__ Wo,
    const float* __restrict__ W1, const float* __restrict__ W2,
    const float* __restrict__ bq, const float* __restrict__ bk,
    const float* __restrict__ bv,
    unsigned short* __restrict__ srcb, unsigned short* __restrict__ Wqkv_t,
    unsigned short* __restrict__ Wo_t, unsigned short* __restrict__ W1_t,
    unsigned short* __restrict__ W2_t, float* __restrict__ bqkv)
{
    int idx = blockIdx.x * 256 + threadIdx.x;
    if (idx < 2097152) { srcb[idx] = f2bf(src[idx]); return; }
    int i = idx - 2097152;
    if (i < 196608) {                       // Wqkv_t [768][256]
        const int c = i >> 8, d = i & 255;
        const int which = c >> 8, h = (c >> 5) & 7, kk = c & 31;
        const float* W = which == 0 ? Wq : which == 1 ? Wk : Wv;
        Wqkv_t[i] = f2bf(W[h * 8192 + d * 32 + kk]);
        return;
    }
    i -= 196608;
    if (i < 65536) {                        // Wo_t [256][256]
        const int n = i >> 8, k2 = i & 255;
        Wo_t[i] = f2bf(Wo[k2 * 256 + n]);
        return;
    }
    i -= 65536;
    if (i < 262144) {                       // W1_t [1024][256]
        const int n = i >> 8, k2 = i & 255;
        W1_t[i] = f2bf(W1[k2 * 1024 + n]);
        return;
    }
    i -= 262144;
    if (i < 262144) {                       // W2_t [256][1024]
        const int n = i >> 10, k2 = i & 1023;
        W2_t[i] = f2bf(W2[k2 * 256 + n]);
        return;
    }
    i -= 262144;
    if (i < 768)
        bqkv[i] = (i < 256) ? bq[i] : (i < 512) ? bk[i - 256] : bv[i - 512];
}

// ---------------------------------------------------------------------------
// K1: bf16 MFMA GEMM.  C[M,N] = A[M,K] @ Bt[N,K]^T (+bias, epilogue variants)
// BM x 64 tile, BK=32; 256 threads = 4 waves (2x2).  Register-prefetched
// staging (next k-tile global loads issued before compute).
// EPI 0: fp32 out = acc + bias + Rres
// EPI 1: bf16 out = relu(acc + bias)
// EPI 2: qkv scatter: bf16 out to qkv[which][B,H,S,32], q scaled by SCALE2
// ---------------------------------------------------------------------------
#define LDA 36   // padded LDS row stride (shorts) = 72 B

template <int EPI, int K, int BM>
__global__ __launch_bounds__(256) void mfma_gemm_k(
    const unsigned short* __restrict__ A,
    const unsigned short* __restrict__ Bt,
    const float* __restrict__ bias,
    const float* __restrict__ Rres,
    void* __restrict__ Cout, int N)
{
    constexpr int MI = BM / 32;                // 16-row frags per wave row-dim
    __shared__ unsigned short Al[BM * LDA];
    __shared__ unsigned short Bl[64 * LDA];

    const int tid  = threadIdx.x;
    const int w    = tid >> 6, lane = tid & 63;
    const int lq   = lane & 15, lk = lane >> 4;
    const int wr   = w >> 1,   wc = w & 1;
    const int m0   = blockIdx.y * BM, n0 = blockIdx.x * 64;

    // staging roles
    const int arow = (BM == 128) ? (tid >> 1) : (tid >> 2);
    const int ac   = (BM == 128) ? ((tid & 1) * 16) : ((tid & 3) * 8);
    const int brow = tid >> 2, bc = (tid & 3) * 8;
    const unsigned short* Ap = A  + (size_t)(m0 + arow) * K + ac;
    const unsigned short* Bp = Bt + (size_t)(n0 + brow) * K + bc;

    f32x4 acc[MI][2];
#pragma unroll
    for (int mi = 0; mi < MI; ++mi)
#pragma unroll
        for (int ni = 0; ni < 2; ++ni) acc[mi][ni] = (f32x4){0.f, 0.f, 0.f, 0.f};

    int4 a0, a1, b0;
    a0 = *(const int4*)(Ap);
    if constexpr (BM == 128) a1 = *(const int4*)(Ap + 8);
    b0 = *(const int4*)(Bp);

    for (int k0 = 0; k0 < K; k0 += 32) {
        __syncthreads();
        *(int4*)&Al[arow * LDA + ac] = a0;
        if constexpr (BM == 128) *(int4*)&Al[arow * LDA + ac + 8] = a1;
        *(int4*)&Bl[brow * LDA + bc] = b0;
        __syncthreads();
        if (k0 + 32 < K) {                    // prefetch next k-tile
            a0 = *(const int4*)(Ap + k0 + 32);
            if constexpr (BM == 128) a1 = *(const int4*)(Ap + k0 + 40);
            b0 = *(const int4*)(Bp + k0 + 32);
        }

        bf16x8 bfrag[2];
#pragma unroll
        for (int ni = 0; ni < 2; ++ni)
            bfrag[ni] = *(const bf16x8*)&Bl[(wc * 32 + ni * 16 + lq) * LDA + lk * 8];
#pragma unroll
        for (int mi = 0; mi < MI; ++mi) {
            const bf16x8 afrag =
                *(const bf16x8*)&Al[(wr * (BM / 2) + mi * 16 + lq) * LDA + lk * 8];
#pragma unroll
            for (int ni = 0; ni < 2; ++ni)
                acc[mi][ni] = __builtin_amdgcn_mfma_f32_16x16x32_bf16(
                    afrag, bfrag[ni], acc[mi][ni], 0, 0, 0);
        }
    }

    // epilogue
#pragma unroll
    for (int ni = 0; ni < 2; ++ni) {
        const int col = n0 + wc * 32 + ni * 16 + lq;
        const float bv_ = bias[col];
#pragma unroll
        for (int mi = 0; mi < MI; ++mi) {
#pragma unroll
            for (int r = 0; r < 4; ++r) {
                const int row = m0 + wr * (BM / 2) + mi * 16 + lk * 4 + r;
                float val = acc[mi][ni][r] + bv_;
                if constexpr (EPI == 0) {
                    ((float*)Cout)[(size_t)row * N + col] =
                        val + Rres[(size_t)row * N + col];
                } else if constexpr (EPI == 1) {
                    ((unsigned short*)Cout)[(size_t)row * N + col] =
                        f2bf(fmaxf(val, 0.f));
                } else {
                    const int which = col >> 8, h = (col >> 5) & 7, kk = col & 31;
                    if (which == 0) val *= SCALE2;
                    const int b = row >> 12, s = row & (SS - 1);
                    ((unsigned short*)Cout)[(size_t)which * 2097152 +
                        ((size_t)(b * 8 + h) * SS + s) * 32 + kk] = f2bf(val);
                }
            }
        }
    }
}

// ---------------------------------------------------------------------------
// K2: MFMA flash attention.  4 waves x 16 q-rows; KV tile = 128.
// K staged PERMUTED: global row t -> LDS row rho(t)=(t&7)*16+(t>>3), so QK
// mfma g yields lane-local contiguous t-run [8*lq, 8*lq+8) per q-row ->
// P written as ONE b128 per row.  Defer-max (theta=8, log2 domain).
// All LDS strides multiples of 8 shorts -> aligned balanced b128 access.
// ---------------------------------------------------------------------------
#define KVB 128
#define RK  40    // Kl row stride (shorts), 80 B
#define RVT 136   // Vt row stride (shorts), 272 B
#define RVP 136   // Pl row stride (shorts), 272 B

__global__ __launch_bounds__(256) void attn_mfma_k(
    const unsigned short* __restrict__ qb, const unsigned short* __restrict__ kb,
    const unsigned short* __restrict__ vb, unsigned short* __restrict__ ctxb)
{
    __shared__ unsigned short Kl[KVB * RK];    // 10240 B
    __shared__ unsigned short Vt[32 * RVT];    //  8704 B  (Vt[dv][t])
    __shared__ unsigned short Pl[4][16 * RVP]; // 17408 B  (per-wave P[q][t])

    const int tid  = threadIdx.x;
    const int w    = tid >> 6;
    const int lane = tid & 63;
    const int lq   = lane & 15;
    const int lk   = lane >> 4;
    const int bh   = blockIdx.x;
    const int b    = bh >> 3;
    const int h    = bh & 7;
    const int q0   = blockIdx.y * 64;

    // staging roles
    const int kt   = tid >> 1, kh = (tid & 1) * 16;       // K: 128 rows x 2
    const int krho = ((kt & 7) << 4) | (kt >> 3);         // permuted LDS row
    const int vt   = tid & 127, vh = (tid >> 7) * 16;     // V: 128 rows x 2

    const unsigned short* kg = kb + (size_t)bh * SS * DKK;
    const unsigned short* vg = vb + (size_t)bh * SS * DKK;

    union U16 { int4 i; bf16x8 b; unsigned short s[8]; };

    // Q fragment, loaded once
    U16 uq;
    uq.i = *(const int4*)(qb + ((size_t)bh * SS + q0 + w * 16 + lq) * DKK + lk * 8);
    const bf16x8 aq = uq.b;

    float m_[4], l_[4];
    f32x4 o0 = {0.f, 0.f, 0.f, 0.f};
    f32x4 o1 = {0.f, 0.f, 0.f, 0.f};
#pragma unroll
    for (int r = 0; r < 4; ++r) { m_[r] = -INFINITY; l_[r] = 0.f; }

    // preload tile 0
    int4 ka0 = *(const int4*)(kg + (size_t)kt * DKK + kh);
    int4 ka1 = *(const int4*)(kg + (size_t)kt * DKK + kh + 8);
    int4 va0 = *(const int4*)(vg + (size_t)vt * DKK + vh);
    int4 va1 = *(const int4*)(vg + (size_t)vt * DKK + vh + 8);

    for (int t0 = 0; t0 < SS; t0 += KVB) {
        __syncthreads();   // previous tile fully consumed
        *(int4*)&Kl[krho * RK + kh]     = ka0;
        *(int4*)&Kl[krho * RK + kh + 8] = ka1;
        U16 u0, u1; u0.i = va0; u1.i = va1;
#pragma unroll
        for (int j = 0; j < 8; ++j) {
            Vt[(vh + j) * RVT + vt]     = u0.s[j];
            Vt[(vh + 8 + j) * RVT + vt] = u1.s[j];
        }
        __syncthreads();

        if (t0 + KVB < SS) {   // prefetch next tile into regs (latency hides)
            const unsigned short* kn = kg + (size_t)(t0 + KVB) * DKK;
            const unsigned short* vn = vg + (size_t)(t0 + KVB) * DKK;
            ka0 = *(const int4*)(kn + (size_t)kt * DKK + kh);
            ka1 = *(const int4*)(kn + (size_t)kt * DKK + kh + 8);
            va0 = *(const int4*)(vn + (size_t)vt * DKK + vh);
            va1 = *(const int4*)(vn + (size_t)vt * DKK + vh + 8);
        }

        // QK^T: 8 mfma; acc[g] col lq = S[qrow][t = 8*lq + g]
        f32x4 acc[8];
#pragma unroll
        for (int g = 0; g < 8; ++g) {
            const bf16x8 bk_ = *(const bf16x8*)&Kl[(g * 16 + lq) * RK + lk * 8];
            acc[g] = __builtin_amdgcn_mfma_f32_16x16x32_bf16(
                aq, bk_, (f32x4){0.f, 0.f, 0.f, 0.f}, 0, 0, 0);
        }

        // row max (reg-max over 8 g, then shfl over the 16 lq lanes)
        float rm[4];
#pragma unroll
        for (int r = 0; r < 4; ++r) {
            float v = acc[0][r];
#pragma unroll
            for (int g = 1; g < 8; ++g) v = fmaxf(v, acc[g][r]);
            v = fmaxf(v, __shfl_xor(v, 1));
            v = fmaxf(v, __shfl_xor(v, 2));
            v = fmaxf(v, __shfl_xor(v, 4));
            v = fmaxf(v, __shfl_xor(v, 8));
            rm[r] = v;
        }
        // defer-max: rescale only if some row grew by > 8 (log2 domain)
        const bool grow = (rm[0] > m_[0] + 8.f) || (rm[1] > m_[1] + 8.f) ||
                          (rm[2] > m_[2] + 8.f) || (rm[3] > m_[3] + 8.f);
        if (__any(grow)) {
#pragma unroll
            for (int r = 0; r < 4; ++r) {
                const float mn = fmaxf(m_[r], rm[r]);
                const float c  = exp2f(m_[r] - mn);
                m_[r] = mn;
                l_[r] *= c;
                o0[r] *= c;
                o1[r] *= c;
            }
        }
        // P = exp2(S - m), packed b128 write per row
#pragma unroll
        for (int r = 0; r < 4; ++r) {
            U16 pp;
            float s = 0.f;
#pragma unroll
            for (int g = 0; g < 8; ++g) {
                const float p = exp2f(acc[g][r] - m_[r]);
                s += p;
                pp.s[g] = f2bf(p);
            }
            l_[r] += s;
            *(int4*)&Pl[w][(lk * 4 + r) * RVP + lq * 8] = pp.i;
        }

        // PV: O[16q][32dv] += P[16q][128t] * V[128t][32dv]
#pragma unroll
        for (int c2 = 0; c2 < 4; ++c2) {
            const bf16x8 pa = *(const bf16x8*)&Pl[w][lq * RVP + c2 * 32 + lk * 8];
            const bf16x8 v0 = *(const bf16x8*)&Vt[lq * RVT + c2 * 32 + lk * 8];
            o0 = __builtin_amdgcn_mfma_f32_16x16x32_bf16(pa, v0, o0, 0, 0, 0);
            const bf16x8 v1 = *(const bf16x8*)&Vt[(16 + lq) * RVT + c2 * 32 + lk * 8];
            o1 = __builtin_amdgcn_mfma_f32_16x16x32_bf16(pa, v1, o1, 0, 0, 0);
        }
    }

    // epilogue: reduce row-sums over the 16 lq lanes, normalize, bf16 out
#pragma unroll
    for (int r = 0; r < 4; ++r) {
        float ls = l_[r];
        ls += __shfl_xor(ls, 1);
        ls += __shfl_xor(ls, 2);
        ls += __shfl_xor(ls, 4);
        ls += __shfl_xor(ls, 8);
        const float inv = 1.0f / ls;
        const size_t row = (size_t)b * SS + q0 + w * 16 + lk * 4 + r;
        unsigned short* cp = ctxb + row * (HH * DKK) + h * DKK;
        cp[lq]      = f2bf(o0[r] * inv);
        cp[16 + lq] = f2bf(o1[r] * inv);
    }
}

// ---------------------------------------------------------------------------
// K3: LayerNorm rows of 256; optional bf16 secondary output.
// ---------------------------------------------------------------------------
__global__ __launch_bounds__(256) void ln_k(
    const float* __restrict__ y, const float* __restrict__ g,
    const float* __restrict__ be, float* __restrict__ out,
    unsigned short* __restrict__ outb)
{
    const int tid = threadIdx.x;
    const size_t r = blockIdx.x;
    const float val = y[r * DD + tid];
    float s1 = val, s2 = val * val;
#pragma unroll
    for (int i = 1; i < 64; i <<= 1) {
        s1 += __shfl_xor(s1, i, 64);
        s2 += __shfl_xor(s2, i, 64);
    }
    __shared__ float ps1[4], ps2[4];
    const int w = tid >> 6, lane = tid & 63;
    if (lane == 0) { ps1[w] = s1; ps2[w] = s2; }
    __syncthreads();
    const float t1 = ps1[0] + ps1[1] + ps1[2] + ps1[3];
    const float t2 = ps2[0] + ps2[1] + ps2[2] + ps2[3];
    const float mean = t1 * (1.f / DD);
    const float var  = t2 * (1.f / DD) - mean * mean;
    const float rs   = rsqrtf(var + 1e-5f);
    const float res  = (val - mean) * rs * g[tid] + be[tid];
    out[r * DD + tid] = res;
    if (outb) outb[r * DD + tid] = f2bf(res);
}

// ---------------------------------------------------------------------------
extern "C" void kernel_launch(void* const* d_in, const int* in_sizes, int n_in,
                              void* d_out, int out_size, void* d_ws, size_t ws_size,
                              hipStream_t stream)
{
    const float* src  = (const float*)d_in[0];
    const float* Wq   = (const float*)d_in[1];
    const float* bq   = (const float*)d_in[2];
    const float* Wk   = (const float*)d_in[3];
    const float* bk   = (const float*)d_in[4];
    const float* Wv   = (const float*)d_in[5];
    const float* bv   = (const float*)d_in[6];
    const float* Wo   = (const float*)d_in[7];
    const float* bo   = (const float*)d_in[8];
    const float* ln1g = (const float*)d_in[9];
    const float* ln1b = (const float*)d_in[10];
    const float* W1   = (const float*)d_in[11];
    const float* b1   = (const float*)d_in[12];
    const float* W2   = (const float*)d_in[13];
    const float* b2   = (const float*)d_in[14];
    const float* ln2g = (const float*)d_in[15];
    const float* ln2b = (const float*)d_in[16];
    float* out = (float*)d_out;

    // Workspace (42 MB):
    //  [0,8M)   x fp32          [8M,12M)  xb bf16
    //  [12M,16M) srcb bf16      [16M,28M) qb/kb/vb bf16 (4 MB each)
    //  [28M,32M) ctxb bf16      [32M,40M) y1 fp32
    //  hh bf16 16MB = [12M,28M) (aliases srcb+qkv, dead by FFN)
    //  [40M,...) bf16 weights + bqkv
    char* wsb = (char*)d_ws;
    float*          x     = (float*)(wsb);
    unsigned short* xb    = (unsigned short*)(wsb + (size_t) 8 * MB);
    unsigned short* srcb  = (unsigned short*)(wsb + (size_t)12 * MB);
    unsigned short* qb    = (unsigned short*)(wsb + (size_t)16 * MB);
    unsigned short* kb2   = (unsigned short*)(wsb + (size_t)20 * MB);
    unsigned short* vb2   = (unsigned short*)(wsb + (size_t)24 * MB);
    unsigned short* ctxb  = (unsigned short*)(wsb + (size_t)28 * MB);
    float*          y1    = (float*)(wsb + (size_t)32 * MB);
    unsigned short* hh    = (unsigned short*)(wsb + (size_t)12 * MB);
    unsigned short* Wqkv_t= (unsigned short*)(wsb + (size_t)40 * MB);
    unsigned short* Wo_t  = (unsigned short*)(wsb + (size_t)40 * MB + 384 * 1024);
    unsigned short* W1_t  = (unsigned short*)(wsb + (size_t)40 * MB + 512 * 1024);
    unsigned short* W2_t  = (unsigned short*)(wsb + (size_t)40 * MB + 1024 * 1024);
    float*          bqkv  = (float*)(wsb + (size_t)40 * MB + 1536 * 1024);

    // 0. conversions
    convert_k<<<11267, 256, 0, stream>>>(src, Wq, Wk, Wv, Wo, W1, W2, bq, bk, bv,
                                         srcb, Wqkv_t, Wo_t, W1_t, W2_t, bqkv);

    // 1. QKV: srcb @ Wqkv_t^T -> qb/kb/vb (scatter epilogue, q scaled)
    mfma_gemm_k<2, DD, 128><<<dim3(12, 64), 256, 0, stream>>>(
        srcb, Wqkv_t, bqkv, nullptr, qb, 768);

    // 2. flash attention -> ctxb bf16 [B,S,256]
    attn_mfma_k<<<dim3(BB * HH, SS / 64), 256, 0, stream>>>(qb, kb2, vb2, ctxb);

    // 3. ctxb @ Wo_t^T + bo + src -> y1 fp32   (BM=64: 512 blocks)
    mfma_gemm_k<0, DD, 64><<<dim3(4, 128), 256, 0, stream>>>(
        ctxb, Wo_t, bo, src, y1, DD);

    // 4. LN1: y1 -> x fp32 + xb bf16
    ln_k<<<BS, DD, 0, stream>>>(y1, ln1g, ln1b, x, xb);

    // 5. xb @ W1_t^T + b1, relu -> hh bf16
    mfma_gemm_k<1, DD, 128><<<dim3(16, 64), 256, 0, stream>>>(
        xb, W1_t, b1, nullptr, hh, DFFC);

    // 6. hh @ W2_t^T + b2 + x -> out fp32   (BM=64: 512 blocks)
    mfma_gemm_k<0, DFFC, 64><<<dim3(4, 128), 256, 0, stream>>>(
        hh, W2_t, b2, x, out, DD);

    // 7. LN2 in place
    ln_k<<<BS, DD, 0, stream>>>(out, ln2g, ln2b, out, nullptr);
}

// Round 8
// 284.627 us; speedup vs baseline: 5.8570x; 1.0576x over previous
//
#include <hip/hip_runtime.h>
#include <hip/hip_bf16.h>

// Problem constants
#define BB   2
#define SS   4096
#define DD   256
#define HH   8
#define DKK  32
#define DFFC 1024
#define BS   (BB*SS)          // 8192 rows
#define MB   (1024*1024)

// softmax scale folded into q, log2 domain: 1/sqrt(32) * 1/ln(2)
#define SCALE2 (0.17677669529663689f * 1.4426950408889634f)

typedef float f32x4 __attribute__((ext_vector_type(4)));
typedef __bf16 bf16x8 __attribute__((ext_vector_type(8)));

// HW RNE f32->bf16: v_cvt_pk_bf16_f32 packs 2 conversions into 1 u32.
// Non-volatile asm (pure) so the scheduler can move/CSE it.
static __device__ __forceinline__ unsigned int cvtpk2(float lo, float hi) {
    unsigned int r;
    asm("v_cvt_pk_bf16_f32 %0, %1, %2" : "=v"(r) : "v"(lo), "v"(hi));
    return r;
}
static __device__ __forceinline__ unsigned short f2bf(float f) {
    return (unsigned short)cvtpk2(f, 0.0f);
}

// ---------------------------------------------------------------------------
// K0: one-shot conversions (runs every launch; graph-safe).
// ---------------------------------------------------------------------------
__global__ __launch_bounds__(256) void convert_k(
    const float* __restrict__ src,
    const float* __restrict__ Wq, const float* __restrict__ Wk,
    const float* __restrict__ Wv, const float* __restrict__ Wo,
    const float* __restrict__ W1, const float* __restrict__ W2,
    const float* __restrict__ bq, const float* __restrict__ bk,
    const float* __restrict__ bv,
    unsigned short* __restrict__ srcb, unsigned short* __restrict__ Wqkv_t,
    unsigned short* __restrict__ Wo_t, unsigned short* __restrict__ W1_t,
    unsigned short* __restrict__ W2_t, float* __restrict__ bqkv)
{
    int idx = blockIdx.x * 256 + threadIdx.x;
    if (idx < 2097152) { srcb[idx] = f2bf(src[idx]); return; }
    int i = idx - 2097152;
    if (i < 196608) {                       // Wqkv_t [768][256]
        const int c = i >> 8, d = i & 255;
        const int which = c >> 8, h = (c >> 5) & 7, kk = c & 31;
        const float* W = which == 0 ? Wq : which == 1 ? Wk : Wv;
        Wqkv_t[i] = f2bf(W[h * 8192 + d * 32 + kk]);
        return;
    }
    i -= 196608;
    if (i < 65536) {                        // Wo_t [256][256]
        const int n = i >> 8, k2 = i & 255;
        Wo_t[i] = f2bf(Wo[k2 * 256 + n]);
        return;
    }
    i -= 65536;
    if (i < 262144) {                       // W1_t [1024][256]
        const int n = i >> 8, k2 = i & 255;
        W1_t[i] = f2bf(W1[k2 * 1024 + n]);
        return;
    }
    i -= 262144;
    if (i < 262144) {                       // W2_t [256][1024]
        const int n = i >> 10, k2 = i & 1023;
        W2_t[i] = f2bf(W2[k2 * 256 + n]);
        return;
    }
    i -= 262144;
    if (i < 768)
        bqkv[i] = (i < 256) ? bq[i] : (i < 512) ? bk[i - 256] : bv[i - 512];
}

// ---------------------------------------------------------------------------
// K1: bf16 MFMA GEMM.  C[M,N] = A[M,K] @ Bt[N,K]^T (+bias, epilogue variants)
// BM x 64 tile, BK=32; 256 threads = 4 waves (2x2).  Register-prefetched
// staging (next k-tile global loads issued before compute).
// EPI 0: fp32 out = acc + bias + Rres
// EPI 1: bf16 out = relu(acc + bias)
// EPI 2: qkv scatter: bf16 out to qkv[which][B,H,S,32], q scaled by SCALE2
// ---------------------------------------------------------------------------
#define LDA 36   // padded LDS row stride (shorts) = 72 B

template <int EPI, int K, int BM>
__global__ __launch_bounds__(256) void mfma_gemm_k(
    const unsigned short* __restrict__ A,
    const unsigned short* __restrict__ Bt,
    const float* __restrict__ bias,
    const float* __restrict__ Rres,
    void* __restrict__ Cout, int N)
{
    constexpr int MI = BM / 32;                // 16-row frags per wave row-dim
    __shared__ unsigned short Al[BM * LDA];
    __shared__ unsigned short Bl[64 * LDA];

    const int tid  = threadIdx.x;
    const int w    = tid >> 6, lane = tid & 63;
    const int lq   = lane & 15, lk = lane >> 4;
    const int wr   = w >> 1,   wc = w & 1;
    const int m0   = blockIdx.y * BM, n0 = blockIdx.x * 64;

    // staging roles
    const int arow = (BM == 128) ? (tid >> 1) : (tid >> 2);
    const int ac   = (BM == 128) ? ((tid & 1) * 16) : ((tid & 3) * 8);
    const int brow = tid >> 2, bc = (tid & 3) * 8;
    const unsigned short* Ap = A  + (size_t)(m0 + arow) * K + ac;
    const unsigned short* Bp = Bt + (size_t)(n0 + brow) * K + bc;

    f32x4 acc[MI][2];
#pragma unroll
    for (int mi = 0; mi < MI; ++mi)
#pragma unroll
        for (int ni = 0; ni < 2; ++ni) acc[mi][ni] = (f32x4){0.f, 0.f, 0.f, 0.f};

    int4 a0, a1, b0;
    a0 = *(const int4*)(Ap);
    if constexpr (BM == 128) a1 = *(const int4*)(Ap + 8);
    b0 = *(const int4*)(Bp);

    for (int k0 = 0; k0 < K; k0 += 32) {
        __syncthreads();
        *(int4*)&Al[arow * LDA + ac] = a0;
        if constexpr (BM == 128) *(int4*)&Al[arow * LDA + ac + 8] = a1;
        *(int4*)&Bl[brow * LDA + bc] = b0;
        __syncthreads();
        if (k0 + 32 < K) {                    // prefetch next k-tile
            a0 = *(const int4*)(Ap + k0 + 32);
            if constexpr (BM == 128) a1 = *(const int4*)(Ap + k0 + 40);
            b0 = *(const int4*)(Bp + k0 + 32);
        }

        bf16x8 bfrag[2];
#pragma unroll
        for (int ni = 0; ni < 2; ++ni)
            bfrag[ni] = *(const bf16x8*)&Bl[(wc * 32 + ni * 16 + lq) * LDA + lk * 8];
#pragma unroll
        for (int mi = 0; mi < MI; ++mi) {
            const bf16x8 afrag =
                *(const bf16x8*)&Al[(wr * (BM / 2) + mi * 16 + lq) * LDA + lk * 8];
#pragma unroll
            for (int ni = 0; ni < 2; ++ni)
                acc[mi][ni] = __builtin_amdgcn_mfma_f32_16x16x32_bf16(
                    afrag, bfrag[ni], acc[mi][ni], 0, 0, 0);
        }
    }

    // epilogue
#pragma unroll
    for (int ni = 0; ni < 2; ++ni) {
        const int col = n0 + wc * 32 + ni * 16 + lq;
        const float bv_ = bias[col];
#pragma unroll
        for (int mi = 0; mi < MI; ++mi) {
#pragma unroll
            for (int r = 0; r < 4; ++r) {
                const int row = m0 + wr * (BM / 2) + mi * 16 + lk * 4 + r;
                float val = acc[mi][ni][r] + bv_;
                if constexpr (EPI == 0) {
                    ((float*)Cout)[(size_t)row * N + col] =
                        val + Rres[(size_t)row * N + col];
                } else if constexpr (EPI == 1) {
                    ((unsigned short*)Cout)[(size_t)row * N + col] =
                        f2bf(fmaxf(val, 0.f));
                } else {
                    const int which = col >> 8, h = (col >> 5) & 7, kk = col & 31;
                    if (which == 0) val *= SCALE2;
                    const int b = row >> 12, s = row & (SS - 1);
                    ((unsigned short*)Cout)[(size_t)which * 2097152 +
                        ((size_t)(b * 8 + h) * SS + s) * 32 + kk] = f2bf(val);
                }
            }
        }
    }
}

// ---------------------------------------------------------------------------
// K2: MFMA flash attention.  4 waves x 16 q-rows; KV tile = 128.
// K tile logically permuted (global row t at LDS row krho(t)=(t&7)*16+(t>>3))
// so QK mfma g yields lane-local contiguous t-run [8*lq, 8*lq+8) -> P is one
// b128 write per row.  Staged via m173: LINEAR LDS dest (row = tid>>1, <=2-way
// banks) + INVERSE-permuted global source t = ((rho&15)<<3)|(rho>>4).
// Defer-max (theta=8, log2 domain).  P pack via v_cvt_pk_bf16_f32.
// ---------------------------------------------------------------------------
#define KVB 128
#define RK  40    // Kl row stride (shorts), 80 B
#define RVT 136   // Vt row stride (shorts), 272 B
#define RVP 136   // Pl row stride (shorts), 272 B

__global__ __launch_bounds__(256) void attn_mfma_k(
    const unsigned short* __restrict__ qb, const unsigned short* __restrict__ kb,
    const unsigned short* __restrict__ vb, unsigned short* __restrict__ ctxb)
{
    __shared__ unsigned short Kl[KVB * RK];    // 10240 B
    __shared__ unsigned short Vt[32 * RVT];    //  8704 B  (Vt[dv][t])
    __shared__ unsigned short Pl[4][16 * RVP]; // 17408 B  (per-wave P[q][t])

    const int tid  = threadIdx.x;
    const int w    = tid >> 6;
    const int lane = tid & 63;
    const int lq   = lane & 15;
    const int lk   = lane >> 4;
    const int bh   = blockIdx.x;
    const int b    = bh >> 3;
    const int h    = bh & 7;
    const int q0   = blockIdx.y * 64;

    // staging roles.  K: LDS row rho linear per thread-pair; global row is the
    // inverse permutation so LDS content matches krho layout.
    const int rho  = tid >> 1, ksel = tid & 1;
    const int kgt  = ((rho & 15) << 3) | (rho >> 4);      // inv(krho)(rho)
    const int vt   = tid & 127, vh = (tid >> 7) * 16;     // V: 128 rows x 2

    const unsigned short* kg = kb + (size_t)bh * SS * DKK;
    const unsigned short* vg = vb + (size_t)bh * SS * DKK;

    union U16 { int4 i; bf16x8 b; unsigned short s[8]; };

    // Q fragment, loaded once
    U16 uq;
    uq.i = *(const int4*)(qb + ((size_t)bh * SS + q0 + w * 16 + lq) * DKK + lk * 8);
    const bf16x8 aq = uq.b;

    float m_[4], l_[4];
    f32x4 o0 = {0.f, 0.f, 0.f, 0.f};
    f32x4 o1 = {0.f, 0.f, 0.f, 0.f};
#pragma unroll
    for (int r = 0; r < 4; ++r) { m_[r] = -INFINITY; l_[r] = 0.f; }

    // preload tile 0
    int4 ka0 = *(const int4*)(kg + (size_t)kgt * DKK + ksel * 16);
    int4 ka1 = *(const int4*)(kg + (size_t)kgt * DKK + ksel * 16 + 8);
    int4 va0 = *(const int4*)(vg + (size_t)vt * DKK + vh);
    int4 va1 = *(const int4*)(vg + (size_t)vt * DKK + vh + 8);

    for (int t0 = 0; t0 < SS; t0 += KVB) {
        __syncthreads();   // previous tile fully consumed
        *(int4*)&Kl[rho * RK + ksel * 16]     = ka0;
        *(int4*)&Kl[rho * RK + ksel * 16 + 8] = ka1;
        U16 u0, u1; u0.i = va0; u1.i = va1;
#pragma unroll
        for (int j = 0; j < 8; ++j) {
            Vt[(vh + j) * RVT + vt]     = u0.s[j];
            Vt[(vh + 8 + j) * RVT + vt] = u1.s[j];
        }
        __syncthreads();

        if (t0 + KVB < SS) {   // prefetch next tile into regs (latency hides)
            const unsigned short* kn = kg + (size_t)(t0 + KVB) * DKK;
            const unsigned short* vn = vg + (size_t)(t0 + KVB) * DKK;
            ka0 = *(const int4*)(kn + (size_t)kgt * DKK + ksel * 16);
            ka1 = *(const int4*)(kn + (size_t)kgt * DKK + ksel * 16 + 8);
            va0 = *(const int4*)(vn + (size_t)vt * DKK + vh);
            va1 = *(const int4*)(vn + (size_t)vt * DKK + vh + 8);
        }

        // QK^T: 8 mfma; acc[g] col lq = S[qrow][t = 8*lq + g]
        f32x4 acc[8];
#pragma unroll
        for (int g = 0; g < 8; ++g) {
            const bf16x8 bk_ = *(const bf16x8*)&Kl[(g * 16 + lq) * RK + lk * 8];
            acc[g] = __builtin_amdgcn_mfma_f32_16x16x32_bf16(
                aq, bk_, (f32x4){0.f, 0.f, 0.f, 0.f}, 0, 0, 0);
        }

        // row max (reg-max over 8 g, then shfl over the 16 lq lanes)
        float rm[4];
#pragma unroll
        for (int r = 0; r < 4; ++r) {
            float v = acc[0][r];
#pragma unroll
            for (int g = 1; g < 8; ++g) v = fmaxf(v, acc[g][r]);
            v = fmaxf(v, __shfl_xor(v, 1));
            v = fmaxf(v, __shfl_xor(v, 2));
            v = fmaxf(v, __shfl_xor(v, 4));
            v = fmaxf(v, __shfl_xor(v, 8));
            rm[r] = v;
        }
        // defer-max: rescale only if some row grew by > 8 (log2 domain)
        const bool grow = (rm[0] > m_[0] + 8.f) || (rm[1] > m_[1] + 8.f) ||
                          (rm[2] > m_[2] + 8.f) || (rm[3] > m_[3] + 8.f);
        if (__any(grow)) {
#pragma unroll
            for (int r = 0; r < 4; ++r) {
                const float mn = fmaxf(m_[r], rm[r]);
                const float c  = exp2f(m_[r] - mn);
                m_[r] = mn;
                l_[r] *= c;
                o0[r] *= c;
                o1[r] *= c;
            }
        }
        // P = exp2(S - m); pack via 4x v_cvt_pk_bf16_f32 -> one b128 per row
#pragma unroll
        for (int r = 0; r < 4; ++r) {
            float p[8];
            float s = 0.f;
#pragma unroll
            for (int g = 0; g < 8; ++g) {
                p[g] = exp2f(acc[g][r] - m_[r]);
                s += p[g];
            }
            l_[r] += s;
            int4 pi;
            pi.x = (int)cvtpk2(p[0], p[1]);
            pi.y = (int)cvtpk2(p[2], p[3]);
            pi.z = (int)cvtpk2(p[4], p[5]);
            pi.w = (int)cvtpk2(p[6], p[7]);
            *(int4*)&Pl[w][(lk * 4 + r) * RVP + lq * 8] = pi;
        }

        // PV: O[16q][32dv] += P[16q][128t] * V[128t][32dv]
#pragma unroll
        for (int c2 = 0; c2 < 4; ++c2) {
            const bf16x8 pa = *(const bf16x8*)&Pl[w][lq * RVP + c2 * 32 + lk * 8];
            const bf16x8 v0 = *(const bf16x8*)&Vt[lq * RVT + c2 * 32 + lk * 8];
            o0 = __builtin_amdgcn_mfma_f32_16x16x32_bf16(pa, v0, o0, 0, 0, 0);
            const bf16x8 v1 = *(const bf16x8*)&Vt[(16 + lq) * RVT + c2 * 32 + lk * 8];
            o1 = __builtin_amdgcn_mfma_f32_16x16x32_bf16(pa, v1, o1, 0, 0, 0);
        }
    }

    // epilogue: reduce row-sums over the 16 lq lanes, normalize, bf16 out
#pragma unroll
    for (int r = 0; r < 4; ++r) {
        float ls = l_[r];
        ls += __shfl_xor(ls, 1);
        ls += __shfl_xor(ls, 2);
        ls += __shfl_xor(ls, 4);
        ls += __shfl_xor(ls, 8);
        const float inv = 1.0f / ls;
        const size_t row = (size_t)b * SS + q0 + w * 16 + lk * 4 + r;
        unsigned short* cp = ctxb + row * (HH * DKK) + h * DKK;
        cp[lq]      = f2bf(o0[r] * inv);
        cp[16 + lq] = f2bf(o1[r] * inv);
    }
}

// ---------------------------------------------------------------------------
// K3: LayerNorm rows of 256; optional bf16 secondary output.
// ---------------------------------------------------------------------------
__global__ __launch_bounds__(256) void ln_k(
    const float* __restrict__ y, const float* __restrict__ g,
    const float* __restrict__ be, float* __restrict__ out,
    unsigned short* __restrict__ outb)
{
    const int tid = threadIdx.x;
    const size_t r = blockIdx.x;
    const float val = y[r * DD + tid];
    float s1 = val, s2 = val * val;
#pragma unroll
    for (int i = 1; i < 64; i <<= 1) {
        s1 += __shfl_xor(s1, i, 64);
        s2 += __shfl_xor(s2, i, 64);
    }
    __shared__ float ps1[4], ps2[4];
    const int w = tid >> 6, lane = tid & 63;
    if (lane == 0) { ps1[w] = s1; ps2[w] = s2; }
    __syncthreads();
    const float t1 = ps1[0] + ps1[1] + ps1[2] + ps1[3];
    const float t2 = ps2[0] + ps2[1] + ps2[2] + ps2[3];
    const float mean = t1 * (1.f / DD);
    const float var  = t2 * (1.f / DD) - mean * mean;
    const float rs   = rsqrtf(var + 1e-5f);
    const float res  = (val - mean) * rs * g[tid] + be[tid];
    out[r * DD + tid] = res;
    if (outb) outb[r * DD + tid] = f2bf(res);
}

// ---------------------------------------------------------------------------
extern "C" void kernel_launch(void* const* d_in, const int* in_sizes, int n_in,
                              void* d_out, int out_size, void* d_ws, size_t ws_size,
                              hipStream_t stream)
{
    const float* src  = (const float*)d_in[0];
    const float* Wq   = (const float*)d_in[1];
    const float* bq   = (const float*)d_in[2];
    const float* Wk   = (const float*)d_in[3];
    const float* bk   = (const float*)d_in[4];
    const float* Wv   = (const float*)d_in[5];
    const float* bv   = (const float*)d_in[6];
    const float* Wo   = (const float*)d_in[7];
    const float* bo   = (const float*)d_in[8];
    const float* ln1g = (const float*)d_in[9];
    const float* ln1b = (const float*)d_in[10];
    const float* W1   = (const float*)d_in[11];
    const float* b1   = (const float*)d_in[12];
    const float* W2   = (const float*)d_in[13];
    const float* b2   = (const float*)d_in[14];
    const float* ln2g = (const float*)d_in[15];
    const float* ln2b = (const float*)d_in[16];
    float* out = (float*)d_out;

    // Workspace (42 MB):
    //  [0,8M)   x fp32          [8M,12M)  xb bf16
    //  [12M,16M) srcb bf16      [16M,28M) qb/kb/vb bf16 (4 MB each)
    //  [28M,32M) ctxb bf16      [32M,40M) y1 fp32
    //  hh bf16 16MB = [12M,28M) (aliases srcb+qkv, dead by FFN)
    //  [40M,...) bf16 weights + bqkv
    char* wsb = (char*)d_ws;
    float*          x     = (float*)(wsb);
    unsigned short* xb    = (unsigned short*)(wsb + (size_t) 8 * MB);
    unsigned short* srcb  = (unsigned short*)(wsb + (size_t)12 * MB);
    unsigned short* qb    = (unsigned short*)(wsb + (size_t)16 * MB);
    unsigned short* kb2   = (unsigned short*)(wsb + (size_t)20 * MB);
    unsigned short* vb2   = (unsigned short*)(wsb + (size_t)24 * MB);
    unsigned short* ctxb  = (unsigned short*)(wsb + (size_t)28 * MB);
    float*          y1    = (float*)(wsb + (size_t)32 * MB);
    unsigned short* hh    = (unsigned short*)(wsb + (size_t)12 * MB);
    unsigned short* Wqkv_t= (unsigned short*)(wsb + (size_t)40 * MB);
    unsigned short* Wo_t  = (unsigned short*)(wsb + (size_t)40 * MB + 384 * 1024);
    unsigned short* W1_t  = (unsigned short*)(wsb + (size_t)40 * MB + 512 * 1024);
    unsigned short* W2_t  = (unsigned short*)(wsb + (size_t)40 * MB + 1024 * 1024);
    float*          bqkv  = (float*)(wsb + (size_t)40 * MB + 1536 * 1024);

    // 0. conversions
    convert_k<<<11267, 256, 0, stream>>>(src, Wq, Wk, Wv, Wo, W1, W2, bq, bk, bv,
                                         srcb, Wqkv_t, Wo_t, W1_t, W2_t, bqkv);

    // 1. QKV: srcb @ Wqkv_t^T -> qb/kb/vb (scatter epilogue, q scaled)
    mfma_gemm_k<2, DD, 128><<<dim3(12, 64), 256, 0, stream>>>(
        srcb, Wqkv_t, bqkv, nullptr, qb, 768);

    // 2. flash attention -> ctxb bf16 [B,S,256]
    attn_mfma_k<<<dim3(BB * HH, SS / 64), 256, 0, stream>>>(qb, kb2, vb2, ctxb);

    // 3. ctxb @ Wo_t^T + bo + src -> y1 fp32   (BM=64: 512 blocks)
    mfma_gemm_k<0, DD, 64><<<dim3(4, 128), 256, 0, stream>>>(
        ctxb, Wo_t, bo, src, y1, DD);

    // 4. LN1: y1 -> x fp32 + xb bf16
    ln_k<<<BS, DD, 0, stream>>>(y1, ln1g, ln1b, x, xb);

    // 5. xb @ W1_t^T + b1, relu -> hh bf16
    mfma_gemm_k<1, DD, 128><<<dim3(16, 64), 256, 0, stream>>>(
        xb, W1_t, b1, nullptr, hh, DFFC);

    // 6. hh @ W2_t^T + b2 + x -> out fp32   (BM=64: 512 blocks)
    mfma_gemm_k<0, DFFC, 64><<<dim3(4, 128), 256, 0, stream>>>(
        hh, W2_t, b2, x, out, DD);

    // 7. LN2 in place
    ln_k<<<BS, DD, 0, stream>>>(out, ln2g, ln2b, out, nullptr);
}